// Round 6
// baseline (1511.806 us; speedup 1.0000x reference)
//
#include <hip/hip_runtime.h>
#include <cstdint>
#include <cstddef>

// GRU (reset_after=True), B=256 T=512 F=128 H=256, fp32 in/out.
// k0: pack kernel/rec_kernel to fp16 MFMA-fragment order + combined bias,
//     PRESCALED: z,r columns x -log2(e); h columns x -2*log2(e).
// k1: MX = x@Wk + bias (prescaled), stored fp16 fragment-order (201 MB ws)
// k2: persistent recurrence, 16 blocks x 16 batch rows.
//     R5: bf[6][8] (192 regs) pinned resident via empty-asm value definition
//     (defeats load rematerialization — R1..R4 all streamed 393 KB/CU/step of
//     R-fragments from L2, ~6100 cy/step wall). MX prefetch moved to LDS via
//     global_load_lds double-buffer (saves the m-prefetch VGPRs). 2-deep A
//     pipeline. One full __syncthreads/step; all VMEM issued a step early.

typedef _Float16 half8 __attribute__((ext_vector_type(8)));
typedef float floatx4 __attribute__((ext_vector_type(4)));

#define RPACK_OFF   0           // 48*8*64*8 halves = 393216 B
#define WKPACK_OFF  393216      // 48*4*64*8 halves = 196608 B
#define BIASP_OFF   589824      // 768 f32 = 3072 B
#define MXP_OFF     1048576     // 512*16*8*3*64*16 B = 201326592 B

#define NLOG2E  (-1.4426950408889634f)
#define N2LOG2E (-2.8853900817779268f)

#if defined(__has_builtin)
#if __has_builtin(__builtin_amdgcn_rcpf)
#define RCPF(x) __builtin_amdgcn_rcpf(x)
#else
#define RCPF(x) (1.0f/(x))
#endif
#if __has_builtin(__builtin_amdgcn_exp2f)
#define EXP2F(x) __builtin_amdgcn_exp2f(x)
#else
#define EXP2F(x) exp2f(x)
#endif
#else
#define RCPF(x) (1.0f/(x))
#define EXP2F(x) exp2f(x)
#endif

// async global->LDS, 16B per lane; LDS dest is wave-uniform base + lane*16
#define GLL16(gp, lp) __builtin_amdgcn_global_load_lds( \
    (const __attribute__((address_space(1))) void*)(gp), \
    (__attribute__((address_space(3))) void*)(lp), 16, 0, 0)

__device__ __forceinline__ int jt_of(int w, int s) {
    // s=0,1: z tiles 2w,2w+1 | s=2,3: r tiles 16+2w,16+2w+1 | s=4,5: h tiles 32+2w,32+2w+1
    return (s < 2) ? (2 * w + s) : (s < 4) ? (16 + 2 * w + (s - 2)) : (32 + 2 * w + (s - 4));
}

// ---------------- kernel 0: pack + prescale weights ----------------
__global__ void k0_pack(const float* __restrict__ Wk, const float* __restrict__ Rk,
                        const float* __restrict__ bias, char* __restrict__ ws) {
    int tid = blockIdx.x * 256 + threadIdx.x;
    _Float16* Rp = (_Float16*)(ws + RPACK_OFF);
    _Float16* Wp = (_Float16*)(ws + WKPACK_OFF);
    float* bp = (float*)(ws + BIASP_OFF);
    if (tid < 24576) {              // Rpack: jt(48) x kt(8) x lane(64) x 8
        int l = tid & 63, kt = (tid >> 6) & 7, jt = tid >> 9;
        int col = jt * 16 + (l & 15);
        float sc = (col < 512) ? NLOG2E : N2LOG2E;
        int k0 = kt * 32 + (l >> 4) * 8;
        half8 v;
#pragma unroll
        for (int i = 0; i < 8; ++i) v[i] = (_Float16)(sc * Rk[(k0 + i) * 768 + col]);
        *(half8*)(Rp + (size_t)tid * 8) = v;
    } else if (tid < 36864) {       // Wkpack: jt(48) x kt(4) x lane(64) x 8
        int j = tid - 24576;
        int l = j & 63, kt = (j >> 6) & 3, jt = j >> 8;
        int col = jt * 16 + (l & 15);
        float sc = (col < 512) ? NLOG2E : N2LOG2E;
        int k0 = kt * 32 + (l >> 4) * 8;
        half8 v;
#pragma unroll
        for (int i = 0; i < 8; ++i) v[i] = (_Float16)(sc * Wk[(k0 + i) * 768 + col]);
        *(half8*)(Wp + (size_t)j * 8) = v;
    } else if (tid < 37632) {       // bias: z,r get input+rec (prescaled); h input-only
        int c = tid - 36864;
        bp[c] = (c < 512) ? NLOG2E * (bias[c] + bias[768 + c])
                          : N2LOG2E * bias[c];
    }
}

// ---------------- kernel 1: MX GEMM (t fixed, 32 batch rows per block) ----------------
__launch_bounds__(512, 2)
__global__ void k1_mx(const float* __restrict__ x, char* __restrict__ ws) {
    __shared__ __attribute__((aligned(16))) char xl[8192];  // 32 rows x 128 fp16, swizzled
    int bid = blockIdx.x;              // 4096 = 512 t * 8 row-pairs
    int t = bid >> 3, jp = bid & 7;
    int b0 = jp * 32;
    int tid = threadIdx.x;
    int l = tid & 63, w = tid >> 6;
    int l15 = l & 15, hi = l >> 4;
    const _Float16* Wp = (const _Float16*)(ws + WKPACK_OFF);
    const float* bp = (const float*)(ws + BIASP_OFF);
    _Float16* MXp = (_Float16*)(ws + MXP_OFF);

    {   // stage x tile -> fp16 LDS (swizzled)
        int rid = tid >> 4, f8 = (tid & 15) * 8;
        const float* src = x + ((size_t)(b0 + rid) * 512 + (size_t)t) * 128 + f8;
        floatx4 v0 = *(const floatx4*)src;
        floatx4 v1 = *(const floatx4*)(src + 4);
        half8 h;
#pragma unroll
        for (int i = 0; i < 4; ++i) { h[i] = (_Float16)v0[i]; h[4 + i] = (_Float16)v1[i]; }
        int byte = (rid * 256 + f8 * 2) ^ ((rid & 7) << 4);
        *(half8*)(xl + byte) = h;
    }

    half8 wk[6][4];
    floatx4 acA[6], acB[6];
#pragma unroll
    for (int s = 0; s < 6; ++s) {
        int jt = jt_of(w, s);
#pragma unroll
        for (int kt = 0; kt < 4; ++kt)
            wk[s][kt] = *(const half8*)(Wp + ((size_t)(jt * 4 + kt) * 64 + l) * 8);
        float bv = bp[jt * 16 + l15];
        acA[s] = (floatx4){bv, bv, bv, bv};
        acB[s] = (floatx4){bv, bv, bv, bv};
    }
    __syncthreads();

    int hi16 = hi * 16;
#pragma unroll
    for (int kt = 0; kt < 4; ++kt) {
        int r0 = l15, r1 = 16 + l15;
        half8 a0 = *(const half8*)(xl + r0 * 256 + ((kt * 64 + hi16) ^ ((r0 & 7) << 4)));
        half8 a1 = *(const half8*)(xl + r1 * 256 + ((kt * 64 + hi16) ^ ((r1 & 7) << 4)));
#pragma unroll
        for (int s = 0; s < 6; ++s) {
            acA[s] = __builtin_amdgcn_mfma_f32_16x16x32_f16(a0, wk[s][kt], acA[s], 0, 0, 0);
            acB[s] = __builtin_amdgcn_mfma_f32_16x16x32_f16(a1, wk[s][kt], acB[s], 0, 0, 0);
        }
    }

    int g0 = (t * 16 + jp * 2) * 8 + w;    // row-group 0 ; group 1 is g0+8
#pragma unroll
    for (int i = 0; i < 3; ++i) {
        half8 h0, h1;
#pragma unroll
        for (int q = 0; q < 4; ++q) {
            h0[q] = (_Float16)acA[2 * i][q]; h0[4 + q] = (_Float16)acA[2 * i + 1][q];
            h1[q] = (_Float16)acB[2 * i][q]; h1[4 + q] = (_Float16)acB[2 * i + 1][q];
        }
        *(half8*)(MXp + ((size_t)(g0 * 3 + i) * 64 + l) * 8) = h0;
        *(half8*)(MXp + ((size_t)((g0 + 8) * 3 + i) * 64 + l) * 8) = h1;
    }
}

// ---------------- kernel 2: persistent recurrence ----------------
#define MFMA6(A, KT) do { \
    ac0 = __builtin_amdgcn_mfma_f32_16x16x32_f16((A), bf[0][KT], ac0, 0, 0, 0); \
    ac1 = __builtin_amdgcn_mfma_f32_16x16x32_f16((A), bf[1][KT], ac1, 0, 0, 0); \
    ac2 = __builtin_amdgcn_mfma_f32_16x16x32_f16((A), bf[2][KT], ac2, 0, 0, 0); \
    ac3 = __builtin_amdgcn_mfma_f32_16x16x32_f16((A), bf[3][KT], ac3, 0, 0, 0); \
    ac4 = __builtin_amdgcn_mfma_f32_16x16x32_f16((A), bf[4][KT], ac4, 0, 0, 0); \
    ac5 = __builtin_amdgcn_mfma_f32_16x16x32_f16((A), bf[5][KT], ac5, 0, 0, 0); \
} while (0)

__launch_bounds__(512, 1)
__global__ void k2_rec(const float* __restrict__ biasraw, const char* __restrict__ ws,
                       float* __restrict__ out) {
    // h double-buffer 16 KB + MX double-buffer 2x24 KB = 64 KB LDS
    __shared__ __attribute__((aligned(16))) char hl[16384];
    __shared__ __attribute__((aligned(16))) char mxl[2][24576];
    int nb = blockIdx.x;               // 16 blocks, rows [16nb,16nb+16)
    int tid = threadIdx.x;
    int l = tid & 63, w = tid >> 6;
    int l15 = l & 15, hi = l >> 4;
    const _Float16* Rp = (const _Float16*)(ws + RPACK_OFF);

    // persistent R fragments: 6 tiles x 8 k-steps = 192 regs
    half8 bf[6][8];
#pragma unroll
    for (int s = 0; s < 6; ++s) {
        int jt = jt_of(w, s);
#pragma unroll
        for (int kt = 0; kt < 8; ++kt)
            bf[s][kt] = *(const half8*)(Rp + ((size_t)(jt * 8 + kt) * 64 + l) * 8);
    }
    // PIN: each fragment becomes asm-defined -> not rematerializable; must stay
    // in registers. (Zero instructions emitted.)
#pragma unroll
    for (int s = 0; s < 6; ++s)
#pragma unroll
        for (int kt = 0; kt < 8; ++kt)
            asm volatile("" : "+v"(bf[s][kt]));

    float brh0 = N2LOG2E * biasraw[768 + 512 + 32 * w + l15];   // rec_bias h-group
    float brh1 = N2LOG2E * biasraw[768 + 512 + 32 * w + l15 + 16];

    // h0 = 0 into buffer 0
    *(floatx4*)(hl + tid * 16) = (floatx4){0.f, 0.f, 0.f, 0.f};
    float h0q[4] = {0.f, 0.f, 0.f, 0.f}, h1q[4] = {0.f, 0.f, 0.f, 0.f};

    const int arow = l15 * 512;
    const int asw = (l15 & 7) << 4;
    const int hi16 = hi * 16;
#define ARD(KT) (*(const half8*)(hr + (((KT) * 64 + hi16) ^ asw)))

    const int ca2 = (32 * w + l15) * 2;
    const int cb2 = (32 * w + 16 + l15) * 2;

    // MX: global per-lane src; LDS wave slice (uniform dest base, lane*16 implicit)
    const char* mxg = (const char*)(ws + MXP_OFF) + (size_t)(nb * 8 + w) * 3072 + (size_t)l * 16;
    char* mxdst = mxl[0] + w * 3072;               // uniform per wave
    const char* mxrd = mxl[0] + w * 3072 + l * 16; // per-lane read base

    // prologue: MX[0] -> buf 0
    GLL16(mxg, mxdst);
    GLL16(mxg + 1024, mxdst + 1024);
    GLL16(mxg + 2048, mxdst + 2048);

    float* outp = out + (size_t)(nb * 16 + hi * 4) * 256 + 32 * w + l15;

    __syncthreads();   // drains prologue gll (vmcnt) + h zeros (lgkm)

    int rb = 0;        // h read-buffer byte offset (0 / 8192)
    int mb = 0;        // MX read-buffer byte offset (0 / 24576)
    for (int t = 0; t < 512; ++t) {
        // issue next-step MX into the other LDS buffer (drained by this step's barrier)
        {
            const char* gq = mxg + (size_t)(t < 511 ? t + 1 : 511) * 393216;
            char* lq = mxdst + (mb ^ 24576);
            GLL16(gq, lq);
            GLL16(gq + 1024, lq + 1024);
            GLL16(gq + 2048, lq + 2048);
        }
        // deferred out[t-1] stores (values live in h regs) — a full step before the drain
        if (t) {
            float* op = outp + (size_t)(t - 1) * 65536;
#pragma unroll
            for (int q = 0; q < 4; ++q) { op[q * 256] = h0q[q]; op[q * 256 + 16] = h1q[q]; }
        }

        // this step's MX from LDS
        half8 m0 = *(const half8*)(mxrd + mb);
        half8 m1 = *(const half8*)(mxrd + mb + 1024);
        half8 m2 = *(const half8*)(mxrd + mb + 2048);

        const char* hr = hl + rb + arow;
        half8 a0 = ARD(0), a1 = ARD(1);

        floatx4 ac0, ac1, ac2, ac3, ac4, ac5;
#pragma unroll
        for (int q = 0; q < 4; ++q) {
            ac0[q] = (float)m0[q];     ac1[q] = (float)m0[4 + q];
            ac2[q] = (float)m1[q];     ac3[q] = (float)m1[4 + q];
        }
        ac4 = (floatx4){brh0, brh0, brh0, brh0};
        ac5 = (floatx4){brh1, brh1, brh1, brh1};

        // mh += h @ R  (2-deep A pipeline)
        MFMA6(a0, 0); a0 = ARD(2);
        MFMA6(a1, 1); a1 = ARD(3);
        MFMA6(a0, 2); a0 = ARD(4);
        MFMA6(a1, 3); a1 = ARD(5);
        MFMA6(a0, 4); a0 = ARD(6);
        MFMA6(a1, 5); a1 = ARD(7);
        MFMA6(a0, 6);
        MFMA6(a1, 7);

        // gating -> h(t+1) into the OTHER h buffer (prescaled: rcp(1+exp2(.)))
        char* hw_ = hl + (rb ^ 8192);
#pragma unroll
        for (int q = 0; q < 4; ++q) {
            float z0 = RCPF(1.0f + EXP2F(ac0[q]));
            float r0 = RCPF(1.0f + EXP2F(ac2[q]));
            float y0 = (float)m2[q] + r0 * ac4[q];
            float c0 = __builtin_fmaf(2.0f, RCPF(1.0f + EXP2F(y0)), -1.0f);
            float hn0 = __builtin_fmaf(z0, h0q[q] - c0, c0);
            h0q[q] = hn0;
            float z1 = RCPF(1.0f + EXP2F(ac1[q]));
            float r1 = RCPF(1.0f + EXP2F(ac3[q]));
            float y1 = (float)m2[4 + q] + r1 * ac5[q];
            float c1 = __builtin_fmaf(2.0f, RCPF(1.0f + EXP2F(y1)), -1.0f);
            float hn1 = __builtin_fmaf(z1, h1q[q] - c1, c1);
            h1q[q] = hn1;

            int rbase = (4 * hi + q) * 512;
            int sw = ((4 * hi + q) & 7) << 4;
            *(_Float16*)(hw_ + ((rbase + ca2) ^ sw)) = (_Float16)hn0;
            *(_Float16*)(hw_ + ((rbase + cb2) ^ sw)) = (_Float16)hn1;
        }

        // one full barrier per step: lgkm covers h/MX LDS; vmcnt drain is free
        // (gll + stores issued a full step earlier)
        __syncthreads();
        rb ^= 8192;
        mb ^= 24576;
    }
    // final out[511]
    {
        float* op = outp + (size_t)511 * 65536;
#pragma unroll
        for (int q = 0; q < 4; ++q) { op[q * 256] = h0q[q]; op[q * 256 + 16] = h1q[q]; }
    }
#undef ARD
}

extern "C" void kernel_launch(void* const* d_in, const int* in_sizes, int n_in,
                              void* d_out, int out_size, void* d_ws, size_t ws_size,
                              hipStream_t stream) {
    const float* x    = (const float*)d_in[0];   // (256,512,128)
    const float* Wk   = (const float*)d_in[1];   // (128,768)
    const float* Rk   = (const float*)d_in[2];   // (256,768)
    const float* bias = (const float*)d_in[3];   // (2,768)
    float* out = (float*)d_out;                  // (512,256,256)
    char* ws = (char*)d_ws;                      // needs ~193 MiB

    k0_pack<<<147, 256, 0, stream>>>(Wk, Rk, bias, ws);
    k1_mx<<<4096, 512, 0, stream>>>(x, ws);
    k2_rec<<<16, 512, 0, stream>>>(bias, ws, out);
}